// Round 9
// baseline (3973.819 us; speedup 1.0000x reference)
//
#include <hip/hip_runtime.h>

#define B_    64
#define T_    64
#define V_    32000
#define VPAD  32768     // N-tiles padded to 256 for XCD-chunked swizzle
#define E_    512
#define H_    1024
#define G4_   4096      // 4*H
#define TS_   63        // time steps actually computed
#define MROWS 4032      // TS_*B_
#define MPAD  4096
#define BH    (B_ * H_)
#define FPAD  32        // flag padding: 32 dwords = 128 B (one L3 line per flag)

typedef __attribute__((ext_vector_type(8))) short bf16x8;   // 8 bf16 = 4 VGPR
typedef __attribute__((ext_vector_type(4))) float f32x4;
typedef __attribute__((ext_vector_type(4))) unsigned int uint32x4;

__device__ __forceinline__ unsigned short bfbits(float f) {  // fp32 -> bf16 (RNE)
  union { float f; unsigned int u; } cv; cv.f = f;
  unsigned int u = cv.u;
  u += 0x7fffu + ((u >> 16) & 1u);
  return (unsigned short)(u >> 16);
}
__device__ __forceinline__ float bf2f(unsigned short h) {
  union { unsigned int u; float f; } cv; cv.u = ((unsigned int)h) << 16;
  return cv.f;
}
__device__ __forceinline__ float fsig(float x) { return 1.f / (1.f + __expf(-x)); }
__device__ __forceinline__ float ftanh(float x) {
  x = fminf(fmaxf(x, -10.f), 10.f);
  const float e = __expf(2.f * x);
  return (e - 1.f) / (e + 1.f);
}

// ---- device-coherent (sc0 sc1) accesses: bypass the non-coherent per-XCD L2.
__device__ __forceinline__ void store_dword_dc(void* p, unsigned int v) {
  asm volatile("global_store_dword %0, %1, off sc0 sc1" :: "v"(p), "v"(v) : "memory");
}
__device__ __forceinline__ void store_b128_dc(void* p, uint32x4 v) {
  asm volatile("global_store_dwordx4 %0, %1, off sc0 sc1" :: "v"(p), "v"(v) : "memory");
}
__device__ __forceinline__ unsigned int load_dword_dc(const void* p) {
  unsigned int v;
  asm volatile("global_load_dword %0, %1, off sc0 sc1\n\ts_waitcnt vmcnt(0)"
               : "=v"(v) : "v"(p) : "memory");
  return v;
}
// non-temporal fp32 store: streaming hint -> don't retain in caches (no L3 thrash)
__device__ __forceinline__ void store_dword_nt(void* p, float f) {
  union { float f; unsigned int u; } cv; cv.f = f;
  asm volatile("global_store_dword %0, %1, off nt" :: "v"(p), "v"(cv.u) : "memory");
}
// non-temporal loads (streamed data: don't evict L2-resident W)
__device__ __forceinline__ bf16x8 ldnt8(const unsigned short* p) {
  return __builtin_nontemporal_load((const bf16x8*)p);
}
__device__ __forceinline__ unsigned short ldnt1(const unsigned short* p) {
  return __builtin_nontemporal_load(p);
}

// async global->LDS, 16B per lane (wave-uniform LDS base + lane*16)
__device__ __forceinline__ void gload16(const void* g, void* l) {
  __builtin_amdgcn_global_load_lds(
      (const __attribute__((address_space(1))) unsigned int*)g,
      (__attribute__((address_space(3))) unsigned int*)l, 16, 0, 0);
}

// ---------------- elementwise / init kernels ----------------

__global__ void k_cast4(const float4* __restrict__ s, ushort4* __restrict__ d, int n4) {
  int i = blockIdx.x * blockDim.x + threadIdx.x;
  const int st = gridDim.x * blockDim.x;
  for (; i < n4; i += st) {
    const float4 f = s[i];
    ushort4 v;
    v.x = bfbits(f.x); v.y = bfbits(f.y); v.z = bfbits(f.z); v.w = bfbits(f.w);
    d[i] = v;
  }
}

__global__ void k_bias(const float* __restrict__ a, const float* __restrict__ b,
                       float* __restrict__ o, int n) {
  const int i = blockIdx.x * blockDim.x + threadIdx.x;
  if (i < n) o[i] = a[i] + b[i];
}

// X[m][e] = bf16(embed[captions[b][t]][e]), m = t*64+b (t<63); pad rows -> 0
__global__ void k_gather(const float* __restrict__ embed, const int* __restrict__ caps,
                         unsigned short* __restrict__ X) {
  const int i = blockIdx.x * 256 + threadIdx.x;   // 2048 blocks * 256 = MPAD*E_/4 exact
  const int m = i >> 7, e4 = i & 127;             // 128 float4 per row
  ushort4 v;
  if (m < MROWS) {
    const int t = m >> 6, b = m & 63;
    const int idx = caps[b * T_ + t];
    const float4 f = ((const float4*)embed)[(long)idx * (E_ / 4) + e4];
    v.x = bfbits(f.x); v.y = bfbits(f.y); v.z = bfbits(f.z); v.w = bfbits(f.w);
  } else {
    v = make_ushort4(0, 0, 0, 0);
  }
  ((ushort4*)X)[i] = v;
}

// h0/h1 initial slots (bf16) + private fp32 copies of c0/c1 + zero (padded) flags
__global__ void k_init(const float* __restrict__ hidden, const float* __restrict__ cell,
                       unsigned short* __restrict__ H0, unsigned short* __restrict__ H1,
                       float* __restrict__ c0, float* __restrict__ c1,
                       unsigned int* __restrict__ flags) {
  const int i = blockIdx.x * 256 + threadIdx.x;   // 256 blocks -> 65536 = B_*H_ exact
  H0[i] = bfbits(hidden[i]);
  H1[i] = bfbits(hidden[B_ * H_ + i]);
  c0[i] = cell[i];
  c1[i] = cell[B_ * H_ + i];
  if (i < 192 * FPAD) flags[i] = 0u;
}

__global__ void k_zeropad(unsigned short* __restrict__ a, unsigned short* __restrict__ b) {
  const int i = blockIdx.x * 256 + threadIdx.x;   // 65536
  a[i] = 0;
  b[i] = 0;
}

__global__ void k_zero_t0(float4* __restrict__ out4) {
  const int i = blockIdx.x * 256 + threadIdx.x;   // 2000 blocks -> 512000 = B_*V_/4 exact
  const int b = i / (V_ / 4), v = i - b * (V_ / 4);
  out4[(long)b * (T_ * V_ / 4) + v] = make_float4(0.f, 0.f, 0.f, 0.f);
}

// ---------------- big GEMM: C(MPADxN) = A(MPADxK) @ Bm(NxK)^T + bias ----------------
// m97 structure: 128x128 tile, BK=32, global_load_lds(16B), 2 barriers/K-step.
// TO_OUT=false: write bf16 C. TO_OUT=true: fp32 scatter to logits with NT stores.
// SWZ=true (GEMM3): 1D grid 8192, XCD-chunked decode for B-tile L2 reuse.
template <int KDIM, bool TO_OUT, bool SWZ>
__global__ __launch_bounds__(256) void k_gemm(
    const unsigned short* __restrict__ A, const unsigned short* __restrict__ Bm,
    const float* __restrict__ bias, unsigned short* __restrict__ Cb,
    float* __restrict__ Cout, int N) {
  __shared__ unsigned short As[128 * 32];
  __shared__ unsigned short Bs[128 * 32];
  const int tid = threadIdx.x;
  const int w = tid >> 6, l = tid & 63;
  const int wm = (w >> 1) * 64, wn = (w & 1) * 64;
  const int lr = l & 15, lk = (l >> 4) * 8;
  int bx, by;
  if constexpr (SWZ) {
    const int flat = blockIdx.x;          // 8192
    const int k = flat & 7, i = flat >> 3;
    bx = (k << 5) + (i >> 5);             // contiguous 32-col patch per XCD
    by = i & 31;                          // fastest -> B-tile L2 reuse across M
  } else {
    bx = blockIdx.x; by = blockIdx.y;
  }
  const long am0 = (long)by * 128;
  const long bn0 = (long)bx * 128;

  const int u0 = tid, u1 = tid + 256;
  const char* gA0 = (const char*)(A + (am0 + (u0 >> 2)) * KDIM) + (u0 & 3) * 16;
  const char* gA1 = (const char*)(A + (am0 + (u1 >> 2)) * KDIM) + (u1 & 3) * 16;
  const char* gB0 = (const char*)(Bm + (bn0 + (u0 >> 2)) * KDIM) + (u0 & 3) * 16;
  const char* gB1 = (const char*)(Bm + (bn0 + (u1 >> 2)) * KDIM) + (u1 & 3) * 16;
  char* lA0 = (char*)As + u0 * 16; char* lA1 = (char*)As + u1 * 16;
  char* lB0 = (char*)Bs + u0 * 16; char* lB1 = (char*)Bs + u1 * 16;

  f32x4 acc[4][4];
  const f32x4 z = {0.f, 0.f, 0.f, 0.f};
  #pragma unroll
  for (int mi = 0; mi < 4; ++mi)
    #pragma unroll
    for (int ni = 0; ni < 4; ++ni) acc[mi][ni] = z;

  for (int k0 = 0; k0 < KDIM; k0 += 32) {
    __syncthreads();
    gload16(gA0 + (long)k0 * 2, lA0);
    gload16(gA1 + (long)k0 * 2, lA1);
    gload16(gB0 + (long)k0 * 2, lB0);
    gload16(gB1 + (long)k0 * 2, lB1);
    __syncthreads();
    bf16x8 af[4], bfr[4];
    #pragma unroll
    for (int mi = 0; mi < 4; ++mi)
      af[mi] = *(const bf16x8*)(As + (wm + mi * 16 + lr) * 32 + lk);
    #pragma unroll
    for (int ni = 0; ni < 4; ++ni)
      bfr[ni] = *(const bf16x8*)(Bs + (wn + ni * 16 + lr) * 32 + lk);
    #pragma unroll
    for (int mi = 0; mi < 4; ++mi)
      #pragma unroll
      for (int ni = 0; ni < 4; ++ni)
        acc[mi][ni] = __builtin_amdgcn_mfma_f32_16x16x32_bf16(af[mi], bfr[ni], acc[mi][ni], 0, 0, 0);
  }

  #pragma unroll
  for (int ni = 0; ni < 4; ++ni) {
    const int n = (int)bn0 + wn + ni * 16 + lr;
    const float bv = (!TO_OUT || n < V_) ? bias[n] : 0.f;
    #pragma unroll
    for (int mi = 0; mi < 4; ++mi) {
      #pragma unroll
      for (int r = 0; r < 4; ++r) {
        const int m = (int)am0 + wm + mi * 16 + (l >> 4) * 4 + r;
        const float v = acc[mi][ni][r] + bv;
        if constexpr (TO_OUT) {
          if (m < MROWS && n < V_) {
            const int t = m >> 6, b = m & 63;
            store_dword_nt(Cout + (long)(b * T_ + t + 1) * V_ + n, v);
          }
        } else {
          Cb[(long)m * N + n] = bfbits(v);
        }
      }
    }
  }
}

// ---------------- fused 2-layer persistent recurrence (48 fat blocks) ----------------
// team-0 = blocks 0..15:  layer-0, 64 j-cols each; stage s computes h0[s+1].
// team-1 = blocks 16..47: layer-1, 32 j-cols each; h1[s] from h1[s-1] & h0[s].
// Waves in 2x2 (M-half x N-half): each thread holds ALL 4 gates in acc -> cell
// math fully in-register (no gate-exchange LDS). W slices (512 KB/block) read
// from L2 every stage (too big for LDS); streamed operands (h, Xp) use
// non-temporal loads so they don't evict W. Per-stage L3 h-traffic: 12 MB
// (was 40 MB at 192 blocks). Sync protocol identical to R6/R8-validated:
// sc0sc1 write-through h + padded monotone flags + sleep-backoff polls.
__global__ __launch_bounds__(256) void k_fused(
    const unsigned short* __restrict__ Whh0b,  // [4096][1024] bf16
    const unsigned short* __restrict__ Whh1b,  // [4096][1024] bf16
    const unsigned short* __restrict__ Wih1b,  // [4096][1024] bf16
    const unsigned short* __restrict__ Xp,     // [63][64][4096] bf16 (x-proj + b0)
    unsigned short* __restrict__ H0b,          // [65][64][1024] bf16, slot 0 init
    unsigned short* __restrict__ H1b,          // [65][64][1024] bf16, slot 0 init
    const float* __restrict__ c0i, const float* __restrict__ c1i,
    const float* __restrict__ b1s,             // [4096] f32
    unsigned int* __restrict__ f0,             // [16*FPAD] zeroed
    unsigned int* __restrict__ f1) {           // [32*FPAD] zeroed
  __shared__ unsigned short hex0[64][64];      // 8 KB h-exchange (store coalescing)
  const int tid = threadIdx.x;
  const int w = tid >> 6, l = tid & 63;
  const int lr = l & 15, khi = l >> 4;
  const int wm = w >> 1, wn = w & 1;
  const int bw = wm * 32;

  if (blockIdx.x < 16) {
    // ================= TEAM 0 : layer 0 (16 blocks x 64 j-cols) =================
    const int blk = blockIdx.x, jb = blk << 6;
    float cr[16];                                 // c-state [mf][js][r]
    #pragma unroll
    for (int mf = 0; mf < 2; ++mf)
      #pragma unroll
      for (int js = 0; js < 2; ++js)
        #pragma unroll
        for (int r = 0; r < 4; ++r)
          cr[(mf * 2 + js) * 4 + r] =
              c0i[(size_t)(bw + mf * 16 + khi * 4 + r) * H_ + jb + wn * 32 + js * 16 + lr];
    const unsigned short* wb[8];                  // W row-frag base per N-frag
    #pragma unroll
    for (int nf = 0; nf < 8; ++nf) {
      const int g = nf >> 1, js = nf & 1;
      wb[nf] = Whh0b + (size_t)(g * 1024 + jb + wn * 32 + js * 16 + lr) * H_ + khi * 8;
    }

    for (int s = 0; s < TS_; ++s) {
      if (s > 0) {
        if (tid < 16)
          while (load_dword_dc(&f0[tid << 5]) < (unsigned)s) __builtin_amdgcn_s_sleep(1);
        __syncthreads();
      }
      // acc init = x-projection (+b0), nt scalar loads
      const unsigned short* xs = Xp + (size_t)s * (B_ * G4_);
      f32x4 acc[2][8];
      #pragma unroll
      for (int mf = 0; mf < 2; ++mf)
        #pragma unroll
        for (int nf = 0; nf < 8; ++nf) {
          const int g = nf >> 1, js = nf & 1;
          const size_t cb = (size_t)(g * 1024 + jb + wn * 32 + js * 16 + lr);
          #pragma unroll
          for (int r = 0; r < 4; ++r)
            acc[mf][nf][r] = bf2f(ldnt1(xs + (size_t)(bw + mf * 16 + khi * 4 + r) * G4_ + cb));
        }
      const unsigned short* a0p = H0b + (size_t)s * BH + (size_t)(bw + lr) * H_ + khi * 8;
      const unsigned short* a1p = a0p + 16 * H_;
      #pragma unroll 4
      for (int kk = 0; kk < 32; ++kk) {
        const bf16x8 av0 = ldnt8(a0p + kk * 32);
        const bf16x8 av1 = ldnt8(a1p + kk * 32);
        #pragma unroll
        for (int nf = 0; nf < 8; ++nf) {
          const bf16x8 bv = *(const bf16x8*)(wb[nf] + kk * 32);
          acc[0][nf] = __builtin_amdgcn_mfma_f32_16x16x32_bf16(av0, bv, acc[0][nf], 0, 0, 0);
          acc[1][nf] = __builtin_amdgcn_mfma_f32_16x16x32_bf16(av1, bv, acc[1][nf], 0, 0, 0);
        }
      }
      // cell update fully in-register (all 4 gates local)
      #pragma unroll
      for (int mf = 0; mf < 2; ++mf)
        #pragma unroll
        for (int js = 0; js < 2; ++js)
          #pragma unroll
          for (int r = 0; r < 4; ++r) {
            const int ci = (mf * 2 + js) * 4 + r;
            const float gi = fsig(acc[mf][0 + js][r]);
            const float gf = fsig(acc[mf][2 + js][r]);
            const float gg = ftanh(acc[mf][4 + js][r]);
            const float go = fsig(acc[mf][6 + js][r]);
            cr[ci] = gf * cr[ci] + gi * gg;
            hex0[bw + mf * 16 + khi * 4 + r][wn * 32 + js * 16 + lr] = bfbits(go * ftanh(cr[ci]));
          }
      __syncthreads();                            // hex0 complete
      {
        unsigned short* hop = H0b + (size_t)(s + 1) * BH;
        const int v0 = tid, v1 = tid + 256;       // 512 16B units: row=u>>3, q=u&7
        store_b128_dc(hop + (size_t)(v0 >> 3) * H_ + jb + (v0 & 7) * 8,
                      *(const uint32x4*)&hex0[v0 >> 3][(v0 & 7) * 8]);
        store_b128_dc(hop + (size_t)(v1 >> 3) * H_ + jb + (v1 & 7) * 8,
                      *(const uint32x4*)&hex0[v1 >> 3][(v1 & 7) * 8]);
      }
      __syncthreads();                            // drain (per-wave vmcnt)
      if (tid == 0) store_dword_dc(&f0[blk << 5], (unsigned)(s + 1));
    }
  } else {
    // ================= TEAM 1 : layer 1 (32 blocks x 32 j-cols) =================
    const int blk1 = blockIdx.x - 16, jb1 = blk1 << 5;
    float cr[8];                                  // c-state [mf][r]
    #pragma unroll
    for (int mf = 0; mf < 2; ++mf)
      #pragma unroll
      for (int r = 0; r < 4; ++r)
        cr[mf * 4 + r] = c1i[(size_t)(bw + mf * 16 + khi * 4 + r) * H_ + jb1 + wn * 16 + lr];
    const unsigned short* wbh[4];
    const unsigned short* wbx[4];
    float bi[4];
    #pragma unroll
    for (int g = 0; g < 4; ++g) {
      const size_t wr = (size_t)(g * 1024 + jb1 + wn * 16 + lr);
      wbh[g] = Whh1b + wr * H_ + khi * 8;
      wbx[g] = Wih1b + wr * H_ + khi * 8;
      bi[g] = b1s[g * 1024 + jb1 + wn * 16 + lr];
    }

    for (int s = 1; s <= TS_; ++s) {
      if (tid < 32) {
        while (load_dword_dc(&f1[tid << 5]) < (unsigned)(s - 1)) __builtin_amdgcn_s_sleep(1);
      } else if (tid < 48) {
        while (load_dword_dc(&f0[(tid - 32) << 5]) < (unsigned)s) __builtin_amdgcn_s_sleep(1);
      }
      __syncthreads();
      f32x4 acc[2][4];
      #pragma unroll
      for (int mf = 0; mf < 2; ++mf)
        #pragma unroll
        for (int g = 0; g < 4; ++g) {
          f32x4 v; v[0] = bi[g]; v[1] = bi[g]; v[2] = bi[g]; v[3] = bi[g];
          acc[mf][g] = v;
        }
      const unsigned short* h1p0 = H1b + (size_t)(s - 1) * BH + (size_t)(bw + lr) * H_ + khi * 8;
      const unsigned short* h1p1 = h1p0 + 16 * H_;
      #pragma unroll 4
      for (int kk = 0; kk < 32; ++kk) {
        const bf16x8 av0 = ldnt8(h1p0 + kk * 32);
        const bf16x8 av1 = ldnt8(h1p1 + kk * 32);
        #pragma unroll
        for (int g = 0; g < 4; ++g) {
          const bf16x8 bv = *(const bf16x8*)(wbh[g] + kk * 32);
          acc[0][g] = __builtin_amdgcn_mfma_f32_16x16x32_bf16(av0, bv, acc[0][g], 0, 0, 0);
          acc[1][g] = __builtin_amdgcn_mfma_f32_16x16x32_bf16(av1, bv, acc[1][g], 0, 0, 0);
        }
      }
      const unsigned short* h0p0 = H0b + (size_t)s * BH + (size_t)(bw + lr) * H_ + khi * 8;
      const unsigned short* h0p1 = h0p0 + 16 * H_;
      #pragma unroll 4
      for (int kk = 0; kk < 32; ++kk) {
        const bf16x8 av0 = ldnt8(h0p0 + kk * 32);
        const bf16x8 av1 = ldnt8(h0p1 + kk * 32);
        #pragma unroll
        for (int g = 0; g < 4; ++g) {
          const bf16x8 bv = *(const bf16x8*)(wbx[g] + kk * 32);
          acc[0][g] = __builtin_amdgcn_mfma_f32_16x16x32_bf16(av0, bv, acc[0][g], 0, 0, 0);
          acc[1][g] = __builtin_amdgcn_mfma_f32_16x16x32_bf16(av1, bv, acc[1][g], 0, 0, 0);
        }
      }
      #pragma unroll
      for (int mf = 0; mf < 2; ++mf)
        #pragma unroll
        for (int r = 0; r < 4; ++r) {
          const int ci = mf * 4 + r;
          const float gi = fsig(acc[mf][0][r]);
          const float gf = fsig(acc[mf][1][r]);
          const float gg = ftanh(acc[mf][2][r]);
          const float go = fsig(acc[mf][3][r]);
          cr[ci] = gf * cr[ci] + gi * gg;
          hex0[bw + mf * 16 + khi * 4 + r][wn * 16 + lr] = bfbits(go * ftanh(cr[ci]));
        }
      __syncthreads();
      {
        unsigned short* hop = H1b + (size_t)s * BH;
        const int u = tid;                        // 256 16B units: row=u>>2, q=u&3
        store_b128_dc(hop + (size_t)(u >> 2) * H_ + jb1 + (u & 3) * 8,
                      *(const uint32x4*)&hex0[u >> 2][(u & 3) * 8]);
      }
      __syncthreads();
      if (tid == 0) store_dword_dc(&f1[blk1 << 5], (unsigned)s);
    }
  }
}

// ---------------- launch ----------------

extern "C" void kernel_launch(void* const* d_in, const int* in_sizes, int n_in,
                              void* d_out, int out_size, void* d_ws, size_t ws_size,
                              hipStream_t stream) {
  (void)in_sizes; (void)n_in; (void)out_size; (void)ws_size;
  const float* hidden = (const float*)d_in[0];
  const float* cell   = (const float*)d_in[1];
  const int*   caps   = (const int*)d_in[2];
  const float* embed  = (const float*)d_in[3];
  const float* Wih0   = (const float*)d_in[4];
  const float* Whh0   = (const float*)d_in[5];
  const float* bih0   = (const float*)d_in[6];
  const float* bhh0   = (const float*)d_in[7];
  const float* Wih1   = (const float*)d_in[8];
  const float* Whh1   = (const float*)d_in[9];
  const float* bih1   = (const float*)d_in[10];
  const float* bhh1   = (const float*)d_in[11];
  const float* Wp     = (const float*)d_in[12];
  const float* bp     = (const float*)d_in[13];
  float* out = (float*)d_out;

  // workspace layout (~150 MB)
  char* p = (char*)d_ws;
  auto alloc = [&](size_t bytes) { char* r = p; p += (bytes + 255) & ~(size_t)255; return r; };
  unsigned short* Xbf   = (unsigned short*)alloc((size_t)MPAD * E_ * 2);
  unsigned short* Wih0b = (unsigned short*)alloc((size_t)G4_ * E_ * 2);
  unsigned short* Whh0b = (unsigned short*)alloc((size_t)G4_ * H_ * 2);
  unsigned short* Wih1b = (unsigned short*)alloc((size_t)G4_ * H_ * 2);
  unsigned short* Whh1b = (unsigned short*)alloc((size_t)G4_ * H_ * 2);
  unsigned short* Wpb   = (unsigned short*)alloc((size_t)VPAD * H_ * 2);  // padded rows
  unsigned short* Xp    = (unsigned short*)alloc((size_t)MPAD * G4_ * 2);
  unsigned short* H0    = (unsigned short*)alloc((size_t)(MPAD + B_) * H_ * 2);  // slots 0..64
  unsigned short* H1    = (unsigned short*)alloc((size_t)(MPAD + B_) * H_ * 2);
  float* c0  = (float*)alloc((size_t)B_ * H_ * 4);
  float* c1  = (float*)alloc((size_t)B_ * H_ * 4);
  float* b0s = (float*)alloc((size_t)G4_ * 4);
  float* b1s = (float*)alloc((size_t)G4_ * 4);
  unsigned int* cbar = (unsigned int*)alloc((size_t)192 * FPAD * 4);  // f0 | f1, padded

  k_cast4<<<2048, 256, 0, stream>>>((const float4*)Wih0, (ushort4*)Wih0b, G4_ * E_ / 4);
  k_cast4<<<2048, 256, 0, stream>>>((const float4*)Whh0, (ushort4*)Whh0b, G4_ * H_ / 4);
  k_cast4<<<2048, 256, 0, stream>>>((const float4*)Wih1, (ushort4*)Wih1b, G4_ * H_ / 4);
  k_cast4<<<2048, 256, 0, stream>>>((const float4*)Whh1, (ushort4*)Whh1b, G4_ * H_ / 4);
  k_cast4<<<4096, 256, 0, stream>>>((const float4*)Wp,   (ushort4*)Wpb,   V_ * H_ / 4);
  k_bias<<<16, 256, 0, stream>>>(bih0, bhh0, b0s, G4_);
  k_bias<<<16, 256, 0, stream>>>(bih1, bhh1, b1s, G4_);
  k_gather<<<2048, 256, 0, stream>>>(embed, caps, Xbf);
  k_init<<<256, 256, 0, stream>>>(hidden, cell, H0, H1, c0, c1, cbar);
  k_zeropad<<<256, 256, 0, stream>>>(H0 + (size_t)MPAD * H_, H1 + (size_t)MPAD * H_);
  k_zero_t0<<<2000, 256, 0, stream>>>((float4*)out);

  // GEMM1: Xp = X @ W_ih0^T + b0   (M=4096, N=4096, K=512)
  k_gemm<512, false, false><<<dim3(32, 32), 256, 0, stream>>>(Xbf, Wih0b, b0s, Xp, nullptr, G4_);

  // fused 2-layer recurrence (48 fat blocks)
  k_fused<<<48, 256, 0, stream>>>(Whh0b, Whh1b, Wih1b, Xp, H0, H1, c0, c1, b1s,
                                  cbar, cbar + 64 * FPAD);

  // GEMM3: logits = H1[1..63] @ Wp^T + bp -> out[:,1:,:]
  // (M=4096(4032), N=32768(32000), K=1024; XCD-chunked 1D grid)
  k_gemm<1024, true, true><<<8192, 256, 0, stream>>>(H1 + (size_t)B_ * H_, Wpb, bp, nullptr, out, V_);
}

// Round 10
// 1319.694 us; speedup vs baseline: 3.0112x; 3.0112x over previous
//
#include <hip/hip_runtime.h>

#define B_    64
#define T_    64
#define V_    32000
#define E_    512
#define H_    1024
#define G4_   4096      // 4*H
#define TS_   63        // time steps actually computed
#define MROWS 4032      // TS_*B_
#define MPAD  4096
#define BH    (B_ * H_)
#define FPAD  32        // flag padding: 32 dwords = 128 B (one L3 line per flag)
#define NTILES 8000     // 32 M-tiles x 250 N-tiles (vocab GEMM)

typedef __attribute__((ext_vector_type(8))) short bf16x8;   // 8 bf16 = 4 VGPR
typedef __attribute__((ext_vector_type(4))) float f32x4;
typedef __attribute__((ext_vector_type(4))) unsigned int uint32x4;

__device__ __forceinline__ unsigned short bfbits(float f) {  // fp32 -> bf16 (RNE)
  union { float f; unsigned int u; } cv; cv.f = f;
  unsigned int u = cv.u;
  u += 0x7fffu + ((u >> 16) & 1u);
  return (unsigned short)(u >> 16);
}
__device__ __forceinline__ float bf2f(unsigned short h) {
  union { unsigned int u; float f; } cv; cv.u = ((unsigned int)h) << 16;
  return cv.f;
}
__device__ __forceinline__ float fsig(float x) { return 1.f / (1.f + __expf(-x)); }
__device__ __forceinline__ float ftanh(float x) {
  x = fminf(fmaxf(x, -10.f), 10.f);
  const float e = __expf(2.f * x);
  return (e - 1.f) / (e + 1.f);
}

// ---- device-coherent (sc0 sc1) accesses: bypass the non-coherent per-XCD L2.
__device__ __forceinline__ void store_dword_dc(void* p, unsigned int v) {
  asm volatile("global_store_dword %0, %1, off sc0 sc1" :: "v"(p), "v"(v) : "memory");
}
__device__ __forceinline__ void store_b128_dc(void* p, uint32x4 v) {
  asm volatile("global_store_dwordx4 %0, %1, off sc0 sc1" :: "v"(p), "v"(v) : "memory");
}
__device__ __forceinline__ unsigned int load_dword_dc(const void* p) {
  unsigned int v;
  asm volatile("global_load_dword %0, %1, off sc0 sc1\n\ts_waitcnt vmcnt(0)"
               : "=v"(v) : "v"(p) : "memory");
  return v;
}
// non-temporal fp32 store: streaming hint -> don't retain in caches
__device__ __forceinline__ void store_dword_nt(void* p, float f) {
  union { float f; unsigned int u; } cv; cv.f = f;
  asm volatile("global_store_dword %0, %1, off nt" :: "v"(p), "v"(cv.u) : "memory");
}

// async global->LDS, 16B per lane (wave-uniform LDS base + lane*16)
__device__ __forceinline__ void gload16(const void* g, void* l) {
  __builtin_amdgcn_global_load_lds(
      (const __attribute__((address_space(1))) unsigned int*)g,
      (__attribute__((address_space(3))) unsigned int*)l, 16, 0, 0);
}

// ---------------- elementwise / init kernels ----------------

__global__ void k_cast4(const float4* __restrict__ s, ushort4* __restrict__ d, int n4) {
  int i = blockIdx.x * blockDim.x + threadIdx.x;
  const int st = gridDim.x * blockDim.x;
  for (; i < n4; i += st) {
    const float4 f = s[i];
    ushort4 v;
    v.x = bfbits(f.x); v.y = bfbits(f.y); v.z = bfbits(f.z); v.w = bfbits(f.w);
    d[i] = v;
  }
}

__global__ void k_bias(const float* __restrict__ a, const float* __restrict__ b,
                       float* __restrict__ o, int n) {
  const int i = blockIdx.x * blockDim.x + threadIdx.x;
  if (i < n) o[i] = a[i] + b[i];
}

// X[m][e] = bf16(embed[captions[b][t]][e]), m = t*64+b (t<63); pad rows -> 0
__global__ void k_gather(const float* __restrict__ embed, const int* __restrict__ caps,
                         unsigned short* __restrict__ X) {
  const int i = blockIdx.x * 256 + threadIdx.x;   // 2048 blocks * 256 = MPAD*E_/4 exact
  const int m = i >> 7, e4 = i & 127;             // 128 float4 per row
  ushort4 v;
  if (m < MROWS) {
    const int t = m >> 6, b = m & 63;
    const int idx = caps[b * T_ + t];
    const float4 f = ((const float4*)embed)[(long)idx * (E_ / 4) + e4];
    v.x = bfbits(f.x); v.y = bfbits(f.y); v.z = bfbits(f.z); v.w = bfbits(f.w);
  } else {
    v = make_ushort4(0, 0, 0, 0);
  }
  ((ushort4*)X)[i] = v;
}

// h0/h1 initial slots (bf16) + private fp32 copies of c0/c1 + zero flags & counter
__global__ void k_init(const float* __restrict__ hidden, const float* __restrict__ cell,
                       unsigned short* __restrict__ H0, unsigned short* __restrict__ H1,
                       float* __restrict__ c0, float* __restrict__ c1,
                       unsigned int* __restrict__ flags) {
  const int i = blockIdx.x * 256 + threadIdx.x;   // 256 blocks -> 65536 = B_*H_ exact
  H0[i] = bfbits(hidden[i]);
  H1[i] = bfbits(hidden[B_ * H_ + i]);
  c0[i] = cell[i];
  c1[i] = cell[B_ * H_ + i];
  if (i < 256 * FPAD) flags[i] = 0u;              // f0 | f1 | pool counter
}

__global__ void k_zeropad(unsigned short* __restrict__ a, unsigned short* __restrict__ b) {
  const int i = blockIdx.x * 256 + threadIdx.x;   // 65536
  a[i] = 0;
  b[i] = 0;
}

__global__ void k_zero_t0(float4* __restrict__ out4) {
  const int i = blockIdx.x * 256 + threadIdx.x;   // 2000 blocks -> 512000 = B_*V_/4 exact
  const int b = i / (V_ / 4), v = i - b * (V_ / 4);
  out4[(long)b * (T_ * V_ / 4) + v] = make_float4(0.f, 0.f, 0.f, 0.f);
}

// ---------------- GEMM1: C(4096x4096) = A(4096x512) @ Bm(4096x512)^T + bias -> bf16 ----
__global__ __launch_bounds__(256) void k_gemm1(
    const unsigned short* __restrict__ A, const unsigned short* __restrict__ Bm,
    const float* __restrict__ bias, unsigned short* __restrict__ Cb) {
  __shared__ unsigned short As[128 * 32];
  __shared__ unsigned short Bs[128 * 32];
  const int tid = threadIdx.x;
  const int w = tid >> 6, l = tid & 63;
  const int wm = (w >> 1) * 64, wn = (w & 1) * 64;
  const int lr = l & 15, lk = (l >> 4) * 8;
  const long am0 = (long)blockIdx.y * 128;
  const long bn0 = (long)blockIdx.x * 128;

  const int u0 = tid, u1 = tid + 256;
  const char* gA0 = (const char*)(A + (am0 + (u0 >> 2)) * E_) + (u0 & 3) * 16;
  const char* gA1 = (const char*)(A + (am0 + (u1 >> 2)) * E_) + (u1 & 3) * 16;
  const char* gB0 = (const char*)(Bm + (bn0 + (u0 >> 2)) * E_) + (u0 & 3) * 16;
  const char* gB1 = (const char*)(Bm + (bn0 + (u1 >> 2)) * E_) + (u1 & 3) * 16;
  char* lA0 = (char*)As + u0 * 16; char* lA1 = (char*)As + u1 * 16;
  char* lB0 = (char*)Bs + u0 * 16; char* lB1 = (char*)Bs + u1 * 16;

  f32x4 acc[4][4];
  const f32x4 z = {0.f, 0.f, 0.f, 0.f};
  #pragma unroll
  for (int mi = 0; mi < 4; ++mi)
    #pragma unroll
    for (int ni = 0; ni < 4; ++ni) acc[mi][ni] = z;

  for (int k0 = 0; k0 < E_; k0 += 32) {
    __syncthreads();
    gload16(gA0 + (long)k0 * 2, lA0);
    gload16(gA1 + (long)k0 * 2, lA1);
    gload16(gB0 + (long)k0 * 2, lB0);
    gload16(gB1 + (long)k0 * 2, lB1);
    __syncthreads();
    bf16x8 af[4], bfr[4];
    #pragma unroll
    for (int mi = 0; mi < 4; ++mi)
      af[mi] = *(const bf16x8*)(As + (wm + mi * 16 + lr) * 32 + lk);
    #pragma unroll
    for (int ni = 0; ni < 4; ++ni)
      bfr[ni] = *(const bf16x8*)(Bs + (wn + ni * 16 + lr) * 32 + lk);
    #pragma unroll
    for (int mi = 0; mi < 4; ++mi)
      #pragma unroll
      for (int ni = 0; ni < 4; ++ni)
        acc[mi][ni] = __builtin_amdgcn_mfma_f32_16x16x32_bf16(af[mi], bfr[ni], acc[mi][ni], 0, 0, 0);
  }

  #pragma unroll
  for (int ni = 0; ni < 4; ++ni) {
    const int n = (int)bn0 + wn + ni * 16 + lr;
    const float bv = bias[n];
    #pragma unroll
    for (int mi = 0; mi < 4; ++mi) {
      #pragma unroll
      for (int r = 0; r < 4; ++r) {
        const int m = (int)am0 + wm + mi * 16 + (l >> 4) * 4 + r;
        Cb[(long)m * G4_ + n] = bfbits(acc[mi][ni][r] + bv);
      }
    }
  }
}

// ---------------- fused persistent kernel: recurrence + flag-gated vocab GEMM pool ----
// 256 co-resident blocks (1/CU, 136KB LDS):
//   blocks 0..63:    team-0 layer-0 recurrence (R8-verified), then join pool
//   blocks 64..191:  team-1 layer-1 recurrence (R8-verified), then join pool
//   blocks 192..255: vocab-GEMM pool from the start
// Pool: grab tile tau (t-ordered) from device atomic counter; tile (my,nx) needs
// f1[*] >= min(2*my+2,63) (monotone flags, sleep backoff; producers never wait
// on consumers -> deadlock-free). 128x128/K=1024 m97-style tile, nt fp32 out.
__global__ __launch_bounds__(256) void k_fused(
    const unsigned short* __restrict__ Whh0b,  // [4096][1024] bf16
    const unsigned short* __restrict__ Whh1b,  // [4096][1024] bf16
    const unsigned short* __restrict__ Wih1b,  // [4096][1024] bf16
    const unsigned short* __restrict__ Xp,     // [63][64][4096] bf16 (x-proj + b0)
    unsigned short* __restrict__ H0b,          // [65][64][1024] bf16, slot 0 init
    unsigned short* __restrict__ H1b,          // [65+][64][1024] bf16, slot 0 init
    const float* __restrict__ c0i, const float* __restrict__ c1i,
    const float* __restrict__ b1s,             // [4096] f32
    const unsigned short* __restrict__ Wpb,    // [32000][1024] bf16
    const float* __restrict__ bp,              // [32000] f32
    float* __restrict__ out,                   // [64][64][32000] f32
    unsigned int* __restrict__ f0,             // [64*FPAD]  zeroed
    unsigned int* __restrict__ f1,             // [128*FPAD] zeroed
    unsigned int* __restrict__ ctr) {          // [1] zeroed pool counter
  __shared__ unsigned short Wl[64 * 1024];     // 128 KB (recur W / pool As+Bs alias)
  __shared__ __align__(16) float gs1[4][64][8];  // 8 KB gate-exchange / h-exchange
  __shared__ int poolSh;
  unsigned short (*hexch)[16] = (unsigned short (*)[16])gs1;

  const int tid = threadIdx.x;
  const int w = tid >> 6, l = tid & 63;
  const int lcol = l & 15, khi = l >> 4;
  const int bw = w * 16;
  const f32x4 z = {0.f, 0.f, 0.f, 0.f};

  if (blockIdx.x < 64) {
    // ================= TEAM 0 : layer 0 =================
    const int blk = blockIdx.x;
    const int jb = blk << 4;
    for (int u = tid; u < 64 * 128; u += 256) {
      const int rr = u >> 7, cu = u & 127;
      const int g = rr >> 4, jj = rr & 15;
      ((bf16x8*)Wl)[rr * 128 + (cu ^ (rr & 7))] =
          *(const bf16x8*)(Whh0b + (size_t)(g * 1024 + jb + jj) * H_ + cu * 8);
    }
    f32x4 cr;
    #pragma unroll
    for (int r = 0; r < 4; ++r)
      cr[r] = c0i[(size_t)(bw + khi * 4 + r) * H_ + jb + lcol];
    unsigned short pin[16];
    #pragma unroll
    for (int r = 0; r < 4; ++r) {
      const unsigned short* ir = Xp + (size_t)(bw + khi * 4 + r) * G4_ + jb + lcol;
      pin[r * 4 + 0] = ir[0];
      pin[r * 4 + 1] = ir[H_];
      pin[r * 4 + 2] = ir[2 * H_];
      pin[r * 4 + 3] = ir[3 * H_];
    }
    __syncthreads();

    for (int s = 0; s < TS_; ++s) {
      if (s > 0) {
        if (tid < 64)
          while (load_dword_dc(&f0[tid << 5]) < (unsigned)s) __builtin_amdgcn_s_sleep(1);
        __syncthreads();
      }
      f32x4 a0, a1, a2, a3;
      #pragma unroll
      for (int r = 0; r < 4; ++r) {
        a0[r] = bf2f(pin[r * 4 + 0]);
        a1[r] = bf2f(pin[r * 4 + 1]);
        a2[r] = bf2f(pin[r * 4 + 2]);
        a3[r] = bf2f(pin[r * 4 + 3]);
      }
      const unsigned short* hrow = H0b + (size_t)s * BH + (size_t)(bw + lcol) * H_ + khi * 8;
      #pragma unroll 8
      for (int kk = 0; kk < 32; ++kk) {
        const bf16x8 av = *(const bf16x8*)(hrow + kk * 32);
        const int un = (kk * 4 + khi) ^ (lcol & 7);
        const bf16x8 b0 = ((const bf16x8*)Wl)[(0 * 16 + lcol) * 128 + un];
        const bf16x8 b1 = ((const bf16x8*)Wl)[(1 * 16 + lcol) * 128 + un];
        const bf16x8 b2 = ((const bf16x8*)Wl)[(2 * 16 + lcol) * 128 + un];
        const bf16x8 b3 = ((const bf16x8*)Wl)[(3 * 16 + lcol) * 128 + un];
        a0 = __builtin_amdgcn_mfma_f32_16x16x32_bf16(av, b0, a0, 0, 0, 0);
        a1 = __builtin_amdgcn_mfma_f32_16x16x32_bf16(av, b1, a1, 0, 0, 0);
        a2 = __builtin_amdgcn_mfma_f32_16x16x32_bf16(av, b2, a2, 0, 0, 0);
        a3 = __builtin_amdgcn_mfma_f32_16x16x32_bf16(av, b3, a3, 0, 0, 0);
      }
      #pragma unroll
      for (int r = 0; r < 4; ++r) {
        const float gi = fsig(a0[r]);
        const float gf = fsig(a1[r]);
        const float gg = ftanh(a2[r]);
        const float go = fsig(a3[r]);
        cr[r] = gf * cr[r] + gi * gg;
        hexch[bw + khi * 4 + r][lcol] = bfbits(go * ftanh(cr[r]));
      }
      if (s + 1 < TS_) {
        const unsigned short* inb = Xp + (size_t)(s + 1) * (B_ * G4_);
        #pragma unroll
        for (int r = 0; r < 4; ++r) {
          const unsigned short* ir = inb + (size_t)(bw + khi * 4 + r) * G4_ + jb + lcol;
          pin[r * 4 + 0] = ir[0];
          pin[r * 4 + 1] = ir[H_];
          pin[r * 4 + 2] = ir[2 * H_];
          pin[r * 4 + 3] = ir[3 * H_];
        }
      }
      __syncthreads();                       // hexch complete
      if (tid < 128) {                       // coalesced 16B device-coherent stores
        const int b = tid >> 1, hf = tid & 1;
        const uint32x4 v = *(const uint32x4*)&hexch[b][hf * 8];
        store_b128_dc(H0b + (size_t)(s + 1) * BH + (size_t)b * H_ + jb + hf * 8, v);
      }
      __syncthreads();                       // drain stores (per-wave vmcnt)
      if (tid == 0) store_dword_dc(&f0[blk << 5], (unsigned)(s + 1));
    }
  } else if (blockIdx.x < 192) {
    // ================= TEAM 1 : layer 1 =================
    const int blk1 = blockIdx.x - 64;
    const int jb1 = blk1 << 3;
    for (int u = tid; u < 64 * 128; u += 256) {
      const int pr = u >> 7, cu = u & 127;
      const int prl = pr & 31, tt = prl >> 4, lr_ = prl & 15;
      const int g = tt * 2 + (lr_ >> 3), jj = lr_ & 7;
      const unsigned short* src =
          ((pr >> 5) ? Wih1b : Whh1b) + (size_t)(g * 1024 + jb1 + jj) * H_ + cu * 8;
      ((bf16x8*)Wl)[pr * 128 + (cu ^ (pr & 7))] = *(const bf16x8*)src;
    }
    const int bb = tid >> 2;
    const int j0 = (tid * 2) & 7;
    float cA = c1i[(size_t)bb * H_ + jb1 + j0];
    float cB = c1i[(size_t)bb * H_ + jb1 + j0 + 1];
    float biA[4], biB[4];
    #pragma unroll
    for (int g = 0; g < 4; ++g) {
      biA[g] = b1s[g * 1024 + jb1 + j0];
      biB[g] = b1s[g * 1024 + jb1 + j0 + 1];
    }
    __syncthreads();

    for (int s = 1; s <= TS_; ++s) {
      {
        const unsigned t0 = (unsigned)s, t1 = (unsigned)(s - 1);
        if (tid < 64) {
          while (load_dword_dc(&f0[tid << 5]) < t0) __builtin_amdgcn_s_sleep(1);
        } else if (tid < 192) {
          while (load_dword_dc(&f1[(tid - 64) << 5]) < t1) __builtin_amdgcn_s_sleep(1);
        }
        __syncthreads();
      }
      f32x4 ac0 = z, ac1 = z;
      const unsigned short* a1p = H1b + (size_t)(s - 1) * BH + (size_t)(bw + lcol) * H_ + khi * 8;
      const unsigned short* a0p = H0b + (size_t)s * BH + (size_t)(bw + lcol) * H_ + khi * 8;
      #pragma unroll 8
      for (int kk = 0; kk < 32; ++kk) {
        const bf16x8 av = *(const bf16x8*)(a1p + kk * 32);
        const int un = (kk * 4 + khi) ^ (lcol & 7);
        const bf16x8 b0 = ((const bf16x8*)Wl)[(0 + lcol) * 128 + un];
        const bf16x8 b1 = ((const bf16x8*)Wl)[(16 + lcol) * 128 + un];
        ac0 = __builtin_amdgcn_mfma_f32_16x16x32_bf16(av, b0, ac0, 0, 0, 0);
        ac1 = __builtin_amdgcn_mfma_f32_16x16x32_bf16(av, b1, ac1, 0, 0, 0);
      }
      #pragma unroll 8
      for (int kk = 0; kk < 32; ++kk) {
        const bf16x8 av = *(const bf16x8*)(a0p + kk * 32);
        const int un = (kk * 4 + khi) ^ (lcol & 7);
        const bf16x8 b0 = ((const bf16x8*)Wl)[(32 + lcol) * 128 + un];
        const bf16x8 b1 = ((const bf16x8*)Wl)[(48 + lcol) * 128 + un];
        ac0 = __builtin_amdgcn_mfma_f32_16x16x32_bf16(av, b0, ac0, 0, 0, 0);
        ac1 = __builtin_amdgcn_mfma_f32_16x16x32_bf16(av, b1, ac1, 0, 0, 0);
      }
      #pragma unroll
      for (int r = 0; r < 4; ++r) {
        const int b = bw + khi * 4 + r;
        gs1[lcol >> 3][b][lcol & 7] = ac0[r];
        gs1[2 + (lcol >> 3)][b][lcol & 7] = ac1[r];
      }
      __syncthreads();
      {
        const float giA = fsig(gs1[0][bb][j0] + biA[0]);
        const float gfA = fsig(gs1[1][bb][j0] + biA[1]);
        const float ggA = ftanh(gs1[2][bb][j0] + biA[2]);
        const float goA = fsig(gs1[3][bb][j0] + biA[3]);
        cA = gfA * cA + giA * ggA;
        const unsigned short hA = bfbits(goA * ftanh(cA));
        const float giB = fsig(gs1[0][bb][j0 + 1] + biB[0]);
        const float gfB = fsig(gs1[1][bb][j0 + 1] + biB[1]);
        const float ggB = ftanh(gs1[2][bb][j0 + 1] + biB[2]);
        const float goB = fsig(gs1[3][bb][j0 + 1] + biB[3]);
        cB = gfB * cB + giB * ggB;
        const unsigned short hB = bfbits(goB * ftanh(cB));
        const unsigned int hv = ((unsigned int)hB << 16) | hA;
        store_dword_dc(H1b + (size_t)s * BH + (size_t)bb * H_ + jb1 + j0, hv);
      }
      __syncthreads();                       // drain stores + gs1 WAR protection
      if (tid == 0) store_dword_dc(&f1[blk1 << 5], (unsigned)s);
    }
  }

  // ================= VOCAB-GEMM POOL (all blocks converge here) =================
  {
    unsigned short* As = Wl;                 // 8 KB
    unsigned short* Bs = Wl + 128 * 32;      // 8 KB
    const unsigned short* Ae = H1b + BH;     // logits A: H1 slots 1..64 (64 = zero pad)
    const int wm = (w >> 1) * 64, wn = (w & 1) * 64;
    const int lr = l & 15, lk = (l >> 4) * 8;

    for (;;) {
      __syncthreads();                       // protect Wl/poolSh reuse across tiles
      if (tid == 0) poolSh = (int)atomicAdd(ctr, 1u);
      __syncthreads();
      const int tau = poolSh;
      if (tau >= NTILES) break;
      const int my = tau / 250, nx = tau - my * 250;
      const unsigned tmax = (unsigned)(2 * my + 2 < 63 ? 2 * my + 2 : 63);
      if (tid < 128)
        while (load_dword_dc(&f1[tid << 5]) < tmax) __builtin_amdgcn_s_sleep(2);
      __syncthreads();

      const long am0 = (long)my * 128;
      const long bn0 = (long)nx * 128;
      const int u0 = tid, u1 = tid + 256;
      const char* gA0 = (const char*)(Ae + (am0 + (u0 >> 2)) * H_) + (u0 & 3) * 16;
      const char* gA1 = (const char*)(Ae + (am0 + (u1 >> 2)) * H_) + (u1 & 3) * 16;
      const char* gB0 = (const char*)(Wpb + (bn0 + (u0 >> 2)) * H_) + (u0 & 3) * 16;
      const char* gB1 = (const char*)(Wpb + (bn0 + (u1 >> 2)) * H_) + (u1 & 3) * 16;
      char* lA0 = (char*)As + u0 * 16; char* lA1 = (char*)As + u1 * 16;
      char* lB0 = (char*)Bs + u0 * 16; char* lB1 = (char*)Bs + u1 * 16;

      f32x4 acc[4][4];
      #pragma unroll
      for (int mi = 0; mi < 4; ++mi)
        #pragma unroll
        for (int ni = 0; ni < 4; ++ni) acc[mi][ni] = z;

      for (int k0 = 0; k0 < H_; k0 += 32) {
        __syncthreads();
        gload16(gA0 + (long)k0 * 2, lA0);
        gload16(gA1 + (long)k0 * 2, lA1);
        gload16(gB0 + (long)k0 * 2, lB0);
        gload16(gB1 + (long)k0 * 2, lB1);
        __syncthreads();
        bf16x8 af[4], bfr[4];
        #pragma unroll
        for (int mi = 0; mi < 4; ++mi)
          af[mi] = *(const bf16x8*)(As + (wm + mi * 16 + lr) * 32 + lk);
        #pragma unroll
        for (int ni = 0; ni < 4; ++ni)
          bfr[ni] = *(const bf16x8*)(Bs + (wn + ni * 16 + lr) * 32 + lk);
        #pragma unroll
        for (int mi = 0; mi < 4; ++mi)
          #pragma unroll
          for (int ni = 0; ni < 4; ++ni)
            acc[mi][ni] = __builtin_amdgcn_mfma_f32_16x16x32_bf16(af[mi], bfr[ni], acc[mi][ni], 0, 0, 0);
      }

      #pragma unroll
      for (int ni = 0; ni < 4; ++ni) {
        const int n = (int)bn0 + wn + ni * 16 + lr;
        const float bv = bp[n];
        #pragma unroll
        for (int mi = 0; mi < 4; ++mi) {
          #pragma unroll
          for (int r = 0; r < 4; ++r) {
            const int m = (int)am0 + wm + mi * 16 + (l >> 4) * 4 + r;
            if (m < MROWS) {
              const int t = m >> 6, b = m & 63;
              store_dword_nt(out + (long)(b * T_ + t + 1) * V_ + n, acc[mi][ni][r] + bv);
            }
          }
        }
      }
    }
  }
}

// ---------------- launch ----------------

extern "C" void kernel_launch(void* const* d_in, const int* in_sizes, int n_in,
                              void* d_out, int out_size, void* d_ws, size_t ws_size,
                              hipStream_t stream) {
  (void)in_sizes; (void)n_in; (void)out_size; (void)ws_size;
  const float* hidden = (const float*)d_in[0];
  const float* cell   = (const float*)d_in[1];
  const int*   caps   = (const int*)d_in[2];
  const float* embed  = (const float*)d_in[3];
  const float* Wih0   = (const float*)d_in[4];
  const float* Whh0   = (const float*)d_in[5];
  const float* bih0   = (const float*)d_in[6];
  const float* bhh0   = (const float*)d_in[7];
  const float* Wih1   = (const float*)d_in[8];
  const float* Whh1   = (const float*)d_in[9];
  const float* bih1   = (const float*)d_in[10];
  const float* bhh1   = (const float*)d_in[11];
  const float* Wp     = (const float*)d_in[12];
  const float* bp     = (const float*)d_in[13];
  float* out = (float*)d_out;

  // workspace layout (~150 MB)
  char* p = (char*)d_ws;
  auto alloc = [&](size_t bytes) { char* r = p; p += (bytes + 255) & ~(size_t)255; return r; };
  unsigned short* Xbf   = (unsigned short*)alloc((size_t)MPAD * E_ * 2);
  unsigned short* Wih0b = (unsigned short*)alloc((size_t)G4_ * E_ * 2);
  unsigned short* Whh0b = (unsigned short*)alloc((size_t)G4_ * H_ * 2);
  unsigned short* Wih1b = (unsigned short*)alloc((size_t)G4_ * H_ * 2);
  unsigned short* Whh1b = (unsigned short*)alloc((size_t)G4_ * H_ * 2);
  unsigned short* Wpb   = (unsigned short*)alloc((size_t)V_ * H_ * 2);
  unsigned short* Xp    = (unsigned short*)alloc((size_t)MPAD * G4_ * 2);
  unsigned short* H0    = (unsigned short*)alloc((size_t)(MPAD + B_) * H_ * 2);  // slots 0..64
  unsigned short* H1    = (unsigned short*)alloc((size_t)(MPAD + B_) * H_ * 2);
  float* c0  = (float*)alloc((size_t)B_ * H_ * 4);
  float* c1  = (float*)alloc((size_t)B_ * H_ * 4);
  float* b0s = (float*)alloc((size_t)G4_ * 4);
  float* b1s = (float*)alloc((size_t)G4_ * 4);
  unsigned int* cbar = (unsigned int*)alloc((size_t)256 * FPAD * 4);  // f0 | f1 | ctr

  k_cast4<<<2048, 256, 0, stream>>>((const float4*)Wih0, (ushort4*)Wih0b, G4_ * E_ / 4);
  k_cast4<<<2048, 256, 0, stream>>>((const float4*)Whh0, (ushort4*)Whh0b, G4_ * H_ / 4);
  k_cast4<<<2048, 256, 0, stream>>>((const float4*)Wih1, (ushort4*)Wih1b, G4_ * H_ / 4);
  k_cast4<<<2048, 256, 0, stream>>>((const float4*)Whh1, (ushort4*)Whh1b, G4_ * H_ / 4);
  k_cast4<<<4096, 256, 0, stream>>>((const float4*)Wp,   (ushort4*)Wpb,   V_ * H_ / 4);
  k_bias<<<16, 256, 0, stream>>>(bih0, bhh0, b0s, G4_);
  k_bias<<<16, 256, 0, stream>>>(bih1, bhh1, b1s, G4_);
  k_gather<<<2048, 256, 0, stream>>>(embed, caps, Xbf);
  k_init<<<256, 256, 0, stream>>>(hidden, cell, H0, H1, c0, c1, cbar);
  k_zeropad<<<256, 256, 0, stream>>>(H0 + (size_t)MPAD * H_, H1 + (size_t)MPAD * H_);
  k_zero_t0<<<2000, 256, 0, stream>>>((float4*)out);

  // GEMM1: Xp = X @ W_ih0^T + b0   (M=4096, N=4096, K=512)
  k_gemm1<<<dim3(32, 32), 256, 0, stream>>>(Xbf, Wih0b, b0s, Xp);

  // fused: 2-layer recurrence (192 blocks, R8-verified) + vocab-GEMM pool (work-stealing)
  k_fused<<<256, 256, 0, stream>>>(Whh0b, Whh1b, Wih1b, Xp, H0, H1, c0, c1, b1s,
                                   Wpb, bp, out,
                                   cbar, cbar + 64 * FPAD, cbar + 192 * FPAD);
}

// Round 11
// 1046.807 us; speedup vs baseline: 3.7961x; 1.2607x over previous
//
#include <hip/hip_runtime.h>

#define B_    64
#define T_    64
#define V_    32000
#define E_    512
#define H_    1024
#define G4_   4096      // 4*H
#define TS_   63        // time steps actually computed
#define MROWS 4032      // TS_*B_
#define MPAD  4096
#define BH    (B_ * H_)
#define FPAD  32        // flag padding: 32 dwords = 128 B (one L3 line per flag)

typedef __attribute__((ext_vector_type(8))) short bf16x8;   // 8 bf16 = 4 VGPR
typedef __attribute__((ext_vector_type(4))) float f32x4;
typedef __attribute__((ext_vector_type(4))) unsigned int uint32x4;

__device__ __forceinline__ unsigned short bfbits(float f) {  // fp32 -> bf16 (RNE)
  union { float f; unsigned int u; } cv; cv.f = f;
  unsigned int u = cv.u;
  u += 0x7fffu + ((u >> 16) & 1u);
  return (unsigned short)(u >> 16);
}
__device__ __forceinline__ float bf2f(unsigned short h) {
  union { unsigned int u; float f; } cv; cv.u = ((unsigned int)h) << 16;
  return cv.f;
}
__device__ __forceinline__ float fsig(float x) { return 1.f / (1.f + __expf(-x)); }
__device__ __forceinline__ float ftanh(float x) {
  x = fminf(fmaxf(x, -10.f), 10.f);
  const float e = __expf(2.f * x);
  return (e - 1.f) / (e + 1.f);
}

// ---- device-coherent (sc0 sc1) accesses: bypass the non-coherent per-XCD L2.
__device__ __forceinline__ void store_dword_dc(void* p, unsigned int v) {
  asm volatile("global_store_dword %0, %1, off sc0 sc1" :: "v"(p), "v"(v) : "memory");
}
__device__ __forceinline__ void store_b128_dc(void* p, uint32x4 v) {
  asm volatile("global_store_dwordx4 %0, %1, off sc0 sc1" :: "v"(p), "v"(v) : "memory");
}
__device__ __forceinline__ unsigned int load_dword_dc(const void* p) {
  unsigned int v;
  asm volatile("global_load_dword %0, %1, off sc0 sc1\n\ts_waitcnt vmcnt(0)"
               : "=v"(v) : "v"(p) : "memory");
  return v;
}
// non-temporal fp32 store: streaming hint -> don't retain in caches
__device__ __forceinline__ void store_dword_nt(void* p, float f) {
  union { float f; unsigned int u; } cv; cv.f = f;
  asm volatile("global_store_dword %0, %1, off nt" :: "v"(p), "v"(cv.u) : "memory");
}

// async global->LDS, 16B per lane (wave-uniform LDS base + lane*16)
__device__ __forceinline__ void gload16(const void* g, void* l) {
  __builtin_amdgcn_global_load_lds(
      (const __attribute__((address_space(1))) unsigned int*)g,
      (__attribute__((address_space(3))) unsigned int*)l, 16, 0, 0);
}

// ---------------- elementwise / init kernels ----------------

__global__ void k_cast4(const float4* __restrict__ s, ushort4* __restrict__ d, int n4) {
  int i = blockIdx.x * blockDim.x + threadIdx.x;
  const int st = gridDim.x * blockDim.x;
  for (; i < n4; i += st) {
    const float4 f = s[i];
    ushort4 v;
    v.x = bfbits(f.x); v.y = bfbits(f.y); v.z = bfbits(f.z); v.w = bfbits(f.w);
    d[i] = v;
  }
}

__global__ void k_bias(const float* __restrict__ a, const float* __restrict__ b,
                       float* __restrict__ o, int n) {
  const int i = blockIdx.x * blockDim.x + threadIdx.x;
  if (i < n) o[i] = a[i] + b[i];
}

// X[m][e] = bf16(embed[captions[b][t]][e]), m = t*64+b (t<63); pad rows -> 0
__global__ void k_gather(const float* __restrict__ embed, const int* __restrict__ caps,
                         unsigned short* __restrict__ X) {
  const int i = blockIdx.x * 256 + threadIdx.x;   // 2048 blocks * 256 = MPAD*E_/4 exact
  const int m = i >> 7, e4 = i & 127;             // 128 float4 per row
  ushort4 v;
  if (m < MROWS) {
    const int t = m >> 6, b = m & 63;
    const int idx = caps[b * T_ + t];
    const float4 f = ((const float4*)embed)[(long)idx * (E_ / 4) + e4];
    v.x = bfbits(f.x); v.y = bfbits(f.y); v.z = bfbits(f.z); v.w = bfbits(f.w);
  } else {
    v = make_ushort4(0, 0, 0, 0);
  }
  ((ushort4*)X)[i] = v;
}

// h0/h1 initial slots (bf16) + private fp32 copies of c0/c1 + zero (padded) flags
__global__ void k_init(const float* __restrict__ hidden, const float* __restrict__ cell,
                       unsigned short* __restrict__ H0, unsigned short* __restrict__ H1,
                       float* __restrict__ c0, float* __restrict__ c1,
                       unsigned int* __restrict__ flags) {
  const int i = blockIdx.x * 256 + threadIdx.x;   // 256 blocks -> 65536 = B_*H_ exact
  H0[i] = bfbits(hidden[i]);
  H1[i] = bfbits(hidden[B_ * H_ + i]);
  c0[i] = cell[i];
  c1[i] = cell[B_ * H_ + i];
  if (i < 192 * FPAD) flags[i] = 0u;
}

__global__ void k_zeropad(unsigned short* __restrict__ a, unsigned short* __restrict__ b) {
  const int i = blockIdx.x * 256 + threadIdx.x;   // 65536
  a[i] = 0;
  b[i] = 0;
}

__global__ void k_zero_t0(float4* __restrict__ out4) {
  const int i = blockIdx.x * 256 + threadIdx.x;   // 2000 blocks -> 512000 = B_*V_/4 exact
  const int b = i / (V_ / 4), v = i - b * (V_ / 4);
  out4[(long)b * (T_ * V_ / 4) + v] = make_float4(0.f, 0.f, 0.f, 0.f);
}

// ---------------- GEMM1: C(4096x4096) = A(4096x512) @ Bm(4096x512)^T + bias -> bf16 ----
__global__ __launch_bounds__(256) void k_gemm1(
    const unsigned short* __restrict__ A, const unsigned short* __restrict__ Bm,
    const float* __restrict__ bias, unsigned short* __restrict__ Cb) {
  __shared__ unsigned short As[128 * 32];
  __shared__ unsigned short Bs[128 * 32];
  const int tid = threadIdx.x;
  const int w = tid >> 6, l = tid & 63;
  const int wm = (w >> 1) * 64, wn = (w & 1) * 64;
  const int lr = l & 15, lk = (l >> 4) * 8;
  const long am0 = (long)blockIdx.y * 128;
  const long bn0 = (long)blockIdx.x * 128;

  const int u0 = tid, u1 = tid + 256;
  const char* gA0 = (const char*)(A + (am0 + (u0 >> 2)) * E_) + (u0 & 3) * 16;
  const char* gA1 = (const char*)(A + (am0 + (u1 >> 2)) * E_) + (u1 & 3) * 16;
  const char* gB0 = (const char*)(Bm + (bn0 + (u0 >> 2)) * E_) + (u0 & 3) * 16;
  const char* gB1 = (const char*)(Bm + (bn0 + (u1 >> 2)) * E_) + (u1 & 3) * 16;
  char* lA0 = (char*)As + u0 * 16; char* lA1 = (char*)As + u1 * 16;
  char* lB0 = (char*)Bs + u0 * 16; char* lB1 = (char*)Bs + u1 * 16;

  f32x4 acc[4][4];
  const f32x4 z = {0.f, 0.f, 0.f, 0.f};
  #pragma unroll
  for (int mi = 0; mi < 4; ++mi)
    #pragma unroll
    for (int ni = 0; ni < 4; ++ni) acc[mi][ni] = z;

  for (int k0 = 0; k0 < E_; k0 += 32) {
    __syncthreads();
    gload16(gA0 + (long)k0 * 2, lA0);
    gload16(gA1 + (long)k0 * 2, lA1);
    gload16(gB0 + (long)k0 * 2, lB0);
    gload16(gB1 + (long)k0 * 2, lB1);
    __syncthreads();
    bf16x8 af[4], bfr[4];
    #pragma unroll
    for (int mi = 0; mi < 4; ++mi)
      af[mi] = *(const bf16x8*)(As + (wm + mi * 16 + lr) * 32 + lk);
    #pragma unroll
    for (int ni = 0; ni < 4; ++ni)
      bfr[ni] = *(const bf16x8*)(Bs + (wn + ni * 16 + lr) * 32 + lk);
    #pragma unroll
    for (int mi = 0; mi < 4; ++mi)
      #pragma unroll
      for (int ni = 0; ni < 4; ++ni)
        acc[mi][ni] = __builtin_amdgcn_mfma_f32_16x16x32_bf16(af[mi], bfr[ni], acc[mi][ni], 0, 0, 0);
  }

  #pragma unroll
  for (int ni = 0; ni < 4; ++ni) {
    const int n = (int)bn0 + wn + ni * 16 + lr;
    const float bv = bias[n];
    #pragma unroll
    for (int mi = 0; mi < 4; ++mi) {
      #pragma unroll
      for (int r = 0; r < 4; ++r) {
        const int m = (int)am0 + wm + mi * 16 + (l >> 4) * 4 + r;
        Cb[(long)m * G4_ + n] = bfbits(acc[mi][ni][r] + bv);
      }
    }
  }
}

// ---------------- GEMM3: logits (256x256 tile, counted vmcnt, swizzled LDS) ----------
// 2000 blocks x 512 threads (8 waves, 2Mx4N). BK=64, double-buffered LDS (128 KB).
// Staging: global_load_lds with PRE-SWIZZLED global source (unit q ^= row&7) and
// linear LDS dest (rule: swizzle both-sides-or-neither); ds_read applies same XOR
// -> 2-way bank aliasing (free) instead of 8-way. Pipeline: stage(t+1) issued
// before compute(t); asm vmcnt(8) + RAW s_barrier keeps next tile's 8 loads in
// flight across the barrier (no vmcnt(0) drain in the main loop).
__global__ __launch_bounds__(512, 2) void k_gemm3(
    const unsigned short* __restrict__ A,    // [4096][1024] bf16 (H1 slots 1..64)
    const unsigned short* __restrict__ Bm,   // [32000][1024] bf16 (Wp)
    const float* __restrict__ bias,          // [32000]
    float* __restrict__ out) {               // [64][64][32000] f32
  __shared__ unsigned short As[2][256 * 64];   // 2 x 32 KB
  __shared__ unsigned short Bs[2][256 * 64];   // 2 x 32 KB
  const int tid = threadIdx.x;
  const int wid = tid >> 6, l = tid & 63;
  const int wr = wid >> 2, wc = wid & 3;       // 2M x 4N wave grid
  const int lr = l & 15, khi = l >> 4;
  const int id = blockIdx.x;
  const int by = id / 125, bx = id - by * 125;
  const long am0 = (long)by * 256;
  const long bn0 = (long)bx * 256;

  // per-thread staging units: idx = j*512 + tid -> row=idx>>3, q=idx&7 (16B units)
  int srow[4], sq[4];
  #pragma unroll
  for (int j = 0; j < 4; ++j) {
    const int idx = j * 512 + tid;
    srow[j] = idx >> 3;
    sq[j] = (idx & 7) ^ (srow[j] & 7);     // pre-swizzled source unit
  }

  f32x4 acc[8][4];
  const f32x4 z = {0.f, 0.f, 0.f, 0.f};
  #pragma unroll
  for (int mf = 0; mf < 8; ++mf)
    #pragma unroll
    for (int nf = 0; nf < 4; ++nf) acc[mf][nf] = z;

  auto stage = [&](int kt, int b) {
    const long koff = (long)kt * 128;      // BK=64 cols * 2B
    #pragma unroll
    for (int j = 0; j < 4; ++j) {
      const int idx = j * 512 + tid;
      gload16((const char*)(A + (am0 + srow[j]) * H_) + koff + sq[j] * 16,
              (char*)As[b] + idx * 16);
    }
    #pragma unroll
    for (int j = 0; j < 4; ++j) {
      const int idx = j * 512 + tid;
      gload16((const char*)(Bm + (bn0 + srow[j]) * H_) + koff + sq[j] * 16,
              (char*)Bs[b] + idx * 16);
    }
  };

  stage(0, 0);
  for (int t = 0; t < 16; ++t) {
    const int c = t & 1;
    __builtin_amdgcn_s_barrier();          // all waves done reading buf c from t-2
    if (t + 1 < 16) {
      stage(t + 1, c ^ 1);
      asm volatile("s_waitcnt vmcnt(8)" ::: "memory");   // tile t done; t+1 in flight
    } else {
      asm volatile("s_waitcnt vmcnt(0)" ::: "memory");
    }
    __builtin_amdgcn_s_barrier();          // tile t staged by ALL waves
    #pragma unroll
    for (int ks = 0; ks < 2; ++ks) {
      const int qx = ((ks * 4 + khi) ^ (lr & 7)) * 16;   // swizzled read unit (bytes)
      bf16x8 af[8], bfr[4];
      #pragma unroll
      for (int mf = 0; mf < 8; ++mf) {
        const int row = wr * 128 + mf * 16 + lr;
        af[mf] = *(const bf16x8*)((const char*)As[c] + row * 128 + qx);
      }
      #pragma unroll
      for (int nf = 0; nf < 4; ++nf) {
        const int row = wc * 64 + nf * 16 + lr;
        bfr[nf] = *(const bf16x8*)((const char*)Bs[c] + row * 128 + qx);
      }
      __builtin_amdgcn_s_setprio(1);
      #pragma unroll
      for (int mf = 0; mf < 8; ++mf)
        #pragma unroll
        for (int nf = 0; nf < 4; ++nf)
          acc[mf][nf] = __builtin_amdgcn_mfma_f32_16x16x32_bf16(af[mf], bfr[nf], acc[mf][nf], 0, 0, 0);
      __builtin_amdgcn_s_setprio(0);
    }
  }

  // epilogue: fp32 nt scatter to out[:,t+1,:]
  #pragma unroll
  for (int nf = 0; nf < 4; ++nf) {
    const int n = (int)bn0 + wc * 64 + nf * 16 + lr;
    const float bv = bias[n];
    #pragma unroll
    for (int mf = 0; mf < 8; ++mf) {
      #pragma unroll
      for (int r = 0; r < 4; ++r) {
        const int m = (int)am0 + wr * 128 + mf * 16 + khi * 4 + r;
        if (m < MROWS) {
          const int t = m >> 6, b = m & 63;
          store_dword_nt(out + (long)(b * T_ + t + 1) * V_ + n, acc[mf][nf][r] + bv);
        }
      }
    }
  }
}

// ---------------- fused 2-layer persistent recurrence (R8-verified lockstep) ----------
// 192 co-resident blocks (1/CU), two teams:
//   team-0 = blocks 0..63:   layer-0, 16 j-cols each; stage s computes h0[s+1].
//   team-1 = blocks 64..191: layer-1, 8 j-cols each; h1[s] from h1[s-1] & h0[s].
// Cross-XCD protocol: sc0sc1 write-through h stores + per-block padded flag array.
// Poll loops use s_sleep backoff.
__global__ __launch_bounds__(256) void k_fused(
    const unsigned short* __restrict__ Whh0b,  // [4096][1024] bf16
    const unsigned short* __restrict__ Whh1b,  // [4096][1024] bf16
    const unsigned short* __restrict__ Wih1b,  // [4096][1024] bf16
    const unsigned short* __restrict__ Xp,     // [63][64][4096] bf16 (x-proj + b0)
    unsigned short* __restrict__ H0b,          // [65][64][1024] bf16, slot 0 init
    unsigned short* __restrict__ H1b,          // [65][64][1024] bf16, slot 0 init
    const float* __restrict__ c0i, const float* __restrict__ c1i,
    const float* __restrict__ b1s,             // [4096] f32
    unsigned int* __restrict__ f0,             // [64*FPAD]  zeroed
    unsigned int* __restrict__ f1) {           // [128*FPAD] zeroed
  __shared__ unsigned short Wl[64 * 1024];     // 128 KB
  __shared__ __align__(16) float gs1[4][64][8];  // 8 KB (team-1); aliased by team-0
  unsigned short (*hexch)[16] = (unsigned short (*)[16])gs1;

  const int tid = threadIdx.x;
  const int w = tid >> 6, l = tid & 63;
  const int lcol = l & 15, khi = l >> 4;
  const int bw = w * 16;
  const f32x4 z = {0.f, 0.f, 0.f, 0.f};

  if (blockIdx.x < 64) {
    // ================= TEAM 0 : layer 0 =================
    const int blk = blockIdx.x;
    const int jb = blk << 4;
    for (int u = tid; u < 64 * 128; u += 256) {
      const int rr = u >> 7, cu = u & 127;
      const int g = rr >> 4, jj = rr & 15;
      ((bf16x8*)Wl)[rr * 128 + (cu ^ (rr & 7))] =
          *(const bf16x8*)(Whh0b + (size_t)(g * 1024 + jb + jj) * H_ + cu * 8);
    }
    f32x4 cr;
    #pragma unroll
    for (int r = 0; r < 4; ++r)
      cr[r] = c0i[(size_t)(bw + khi * 4 + r) * H_ + jb + lcol];
    unsigned short pin[16];
    #pragma unroll
    for (int r = 0; r < 4; ++r) {
      const unsigned short* ir = Xp + (size_t)(bw + khi * 4 + r) * G4_ + jb + lcol;
      pin[r * 4 + 0] = ir[0];
      pin[r * 4 + 1] = ir[H_];
      pin[r * 4 + 2] = ir[2 * H_];
      pin[r * 4 + 3] = ir[3 * H_];
    }
    __syncthreads();

    for (int s = 0; s < TS_; ++s) {
      if (s > 0) {
        if (tid < 64)
          while (load_dword_dc(&f0[tid << 5]) < (unsigned)s) __builtin_amdgcn_s_sleep(1);
        __syncthreads();
      }
      f32x4 a0, a1, a2, a3;
      #pragma unroll
      for (int r = 0; r < 4; ++r) {
        a0[r] = bf2f(pin[r * 4 + 0]);
        a1[r] = bf2f(pin[r * 4 + 1]);
        a2[r] = bf2f(pin[r * 4 + 2]);
        a3[r] = bf2f(pin[r * 4 + 3]);
      }
      const unsigned short* hrow = H0b + (size_t)s * BH + (size_t)(bw + lcol) * H_ + khi * 8;
      #pragma unroll 8
      for (int kk = 0; kk < 32; ++kk) {
        const bf16x8 av = *(const bf16x8*)(hrow + kk * 32);
        const int un = (kk * 4 + khi) ^ (lcol & 7);
        const bf16x8 b0 = ((const bf16x8*)Wl)[(0 * 16 + lcol) * 128 + un];
        const bf16x8 b1 = ((const bf16x8*)Wl)[(1 * 16 + lcol) * 128 + un];
        const bf16x8 b2 = ((const bf16x8*)Wl)[(2 * 16 + lcol) * 128 + un];
        const bf16x8 b3 = ((const bf16x8*)Wl)[(3 * 16 + lcol) * 128 + un];
        a0 = __builtin_amdgcn_mfma_f32_16x16x32_bf16(av, b0, a0, 0, 0, 0);
        a1 = __builtin_amdgcn_mfma_f32_16x16x32_bf16(av, b1, a1, 0, 0, 0);
        a2 = __builtin_amdgcn_mfma_f32_16x16x32_bf16(av, b2, a2, 0, 0, 0);
        a3 = __builtin_amdgcn_mfma_f32_16x16x32_bf16(av, b3, a3, 0, 0, 0);
      }
      #pragma unroll
      for (int r = 0; r < 4; ++r) {
        const float gi = fsig(a0[r]);
        const float gf = fsig(a1[r]);
        const float gg = ftanh(a2[r]);
        const float go = fsig(a3[r]);
        cr[r] = gf * cr[r] + gi * gg;
        hexch[bw + khi * 4 + r][lcol] = bfbits(go * ftanh(cr[r]));
      }
      if (s + 1 < TS_) {
        const unsigned short* inb = Xp + (size_t)(s + 1) * (B_ * G4_);
        #pragma unroll
        for (int r = 0; r < 4; ++r) {
          const unsigned short* ir = inb + (size_t)(bw + khi * 4 + r) * G4_ + jb + lcol;
          pin[r * 4 + 0] = ir[0];
          pin[r * 4 + 1] = ir[H_];
          pin[r * 4 + 2] = ir[2 * H_];
          pin[r * 4 + 3] = ir[3 * H_];
        }
      }
      __syncthreads();                       // hexch complete
      if (tid < 128) {                       // coalesced 16B device-coherent stores
        const int b = tid >> 1, hf = tid & 1;
        const uint32x4 v = *(const uint32x4*)&hexch[b][hf * 8];
        store_b128_dc(H0b + (size_t)(s + 1) * BH + (size_t)b * H_ + jb + hf * 8, v);
      }
      __syncthreads();                       // drain stores (per-wave vmcnt)
      if (tid == 0) store_dword_dc(&f0[blk << 5], (unsigned)(s + 1));
    }
  } else {
    // ================= TEAM 1 : layer 1 =================
    const int blk1 = blockIdx.x - 64;
    const int jb1 = blk1 << 3;
    for (int u = tid; u < 64 * 128; u += 256) {
      const int pr = u >> 7, cu = u & 127;
      const int prl = pr & 31, tt = prl >> 4, lr_ = prl & 15;
      const int g = tt * 2 + (lr_ >> 3), jj = lr_ & 7;
      const unsigned short* src =
          ((pr >> 5) ? Wih1b : Whh1b) + (size_t)(g * 1024 + jb1 + jj) * H_ + cu * 8;
      ((bf16x8*)Wl)[pr * 128 + (cu ^ (pr & 7))] = *(const bf16x8*)src;
    }
    const int bb = tid >> 2;
    const int j0 = (tid * 2) & 7;
    float cA = c1i[(size_t)bb * H_ + jb1 + j0];
    float cB = c1i[(size_t)bb * H_ + jb1 + j0 + 1];
    float biA[4], biB[4];
    #pragma unroll
    for (int g = 0; g < 4; ++g) {
      biA[g] = b1s[g * 1024 + jb1 + j0];
      biB[g] = b1s[g * 1024 + jb1 + j0 + 1];
    }
    __syncthreads();

    for (int s = 1; s <= TS_; ++s) {
      {
        const unsigned t0 = (unsigned)s, t1 = (unsigned)(s - 1);
        if (tid < 64) {
          while (load_dword_dc(&f0[tid << 5]) < t0) __builtin_amdgcn_s_sleep(1);
        } else if (tid < 192) {
          while (load_dword_dc(&f1[(tid - 64) << 5]) < t1) __builtin_amdgcn_s_sleep(1);
        }
        __syncthreads();
      }
      f32x4 ac0 = z, ac1 = z;
      const unsigned short* a1p = H1b + (size_t)(s - 1) * BH + (size_t)(bw + lcol) * H_ + khi * 8;
      const unsigned short* a0p = H0b + (size_t)s * BH + (size_t)(bw + lcol) * H_ + khi * 8;
      #pragma unroll 8
      for (int kk = 0; kk < 32; ++kk) {
        const bf16x8 av = *(const bf16x8*)(a1p + kk * 32);
        const int un = (kk * 4 + khi) ^ (lcol & 7);
        const bf16x8 b0 = ((const bf16x8*)Wl)[(0 + lcol) * 128 + un];
        const bf16x8 b1 = ((const bf16x8*)Wl)[(16 + lcol) * 128 + un];
        ac0 = __builtin_amdgcn_mfma_f32_16x16x32_bf16(av, b0, ac0, 0, 0, 0);
        ac1 = __builtin_amdgcn_mfma_f32_16x16x32_bf16(av, b1, ac1, 0, 0, 0);
      }
      #pragma unroll 8
      for (int kk = 0; kk < 32; ++kk) {
        const bf16x8 av = *(const bf16x8*)(a0p + kk * 32);
        const int un = (kk * 4 + khi) ^ (lcol & 7);
        const bf16x8 b0 = ((const bf16x8*)Wl)[(32 + lcol) * 128 + un];
        const bf16x8 b1 = ((const bf16x8*)Wl)[(48 + lcol) * 128 + un];
        ac0 = __builtin_amdgcn_mfma_f32_16x16x32_bf16(av, b0, ac0, 0, 0, 0);
        ac1 = __builtin_amdgcn_mfma_f32_16x16x32_bf16(av, b1, ac1, 0, 0, 0);
      }
      #pragma unroll
      for (int r = 0; r < 4; ++r) {
        const int b = bw + khi * 4 + r;
        gs1[lcol >> 3][b][lcol & 7] = ac0[r];
        gs1[2 + (lcol >> 3)][b][lcol & 7] = ac1[r];
      }
      __syncthreads();
      {
        const float giA = fsig(gs1[0][bb][j0] + biA[0]);
        const float gfA = fsig(gs1[1][bb][j0] + biA[1]);
        const float ggA = ftanh(gs1[2][bb][j0] + biA[2]);
        const float goA = fsig(gs1[3][bb][j0] + biA[3]);
        cA = gfA * cA + giA * ggA;
        const unsigned short hA = bfbits(goA * ftanh(cA));
        const float giB = fsig(gs1[0][bb][j0 + 1] + biB[0]);
        const float gfB = fsig(gs1[1][bb][j0 + 1] + biB[1]);
        const float ggB = ftanh(gs1[2][bb][j0 + 1] + biB[2]);
        const float goB = fsig(gs1[3][bb][j0 + 1] + biB[3]);
        cB = gfB * cB + giB * ggB;
        const unsigned short hB = bfbits(goB * ftanh(cB));
        const unsigned int hv = ((unsigned int)hB << 16) | hA;
        store_dword_dc(H1b + (size_t)s * BH + (size_t)bb * H_ + jb1 + j0, hv);
      }
      __syncthreads();                       // drain stores + gs1 WAR protection
      if (tid == 0) store_dword_dc(&f1[blk1 << 5], (unsigned)s);
    }
  }
}

// ---------------- launch ----------------

extern "C" void kernel_launch(void* const* d_in, const int* in_sizes, int n_in,
                              void* d_out, int out_size, void* d_ws, size_t ws_size,
                              hipStream_t stream) {
  (void)in_sizes; (void)n_in; (void)out_size; (void)ws_size;
  const float* hidden = (const float*)d_in[0];
  const float* cell   = (const float*)d_in[1];
  const int*   caps   = (const int*)d_in[2];
  const float* embed  = (const float*)d_in[3];
  const float* Wih0   = (const float*)d_in[4];
  const float* Whh0   = (const float*)d_in[5];
  const float* bih0   = (const float*)d_in[6];
  const float* bhh0   = (const float*)d_in[7];
  const float* Wih1   = (const float*)d_in[8];
  const float* Whh1   = (const float*)d_in[9];
  const float* bih1   = (const float*)d_in[10];
  const float* bhh1   = (const float*)d_in[11];
  const float* Wp     = (const float*)d_in[12];
  const float* bp     = (const float*)d_in[13];
  float* out = (float*)d_out;

  // workspace layout (~150 MB)
  char* p = (char*)d_ws;
  auto alloc = [&](size_t bytes) { char* r = p; p += (bytes + 255) & ~(size_t)255; return r; };
  unsigned short* Xbf   = (unsigned short*)alloc((size_t)MPAD * E_ * 2);
  unsigned short* Wih0b = (unsigned short*)alloc((size_t)G4_ * E_ * 2);
  unsigned short* Whh0b = (unsigned short*)alloc((size_t)G4_ * H_ * 2);
  unsigned short* Wih1b = (unsigned short*)alloc((size_t)G4_ * H_ * 2);
  unsigned short* Whh1b = (unsigned short*)alloc((size_t)G4_ * H_ * 2);
  unsigned short* Wpb   = (unsigned short*)alloc((size_t)V_ * H_ * 2);
  unsigned short* Xp    = (unsigned short*)alloc((size_t)MPAD * G4_ * 2);
  unsigned short* H0    = (unsigned short*)alloc((size_t)(MPAD + B_) * H_ * 2);  // slots 0..64
  unsigned short* H1    = (unsigned short*)alloc((size_t)(MPAD + B_) * H_ * 2);
  float* c0  = (float*)alloc((size_t)B_ * H_ * 4);
  float* c1  = (float*)alloc((size_t)B_ * H_ * 4);
  float* b0s = (float*)alloc((size_t)G4_ * 4);
  float* b1s = (float*)alloc((size_t)G4_ * 4);
  unsigned int* cbar = (unsigned int*)alloc((size_t)192 * FPAD * 4);  // f0 | f1, padded

  k_cast4<<<2048, 256, 0, stream>>>((const float4*)Wih0, (ushort4*)Wih0b, G4_ * E_ / 4);
  k_cast4<<<2048, 256, 0, stream>>>((const float4*)Whh0, (ushort4*)Whh0b, G4_ * H_ / 4);
  k_cast4<<<2048, 256, 0, stream>>>((const float4*)Wih1, (ushort4*)Wih1b, G4_ * H_ / 4);
  k_cast4<<<2048, 256, 0, stream>>>((const float4*)Whh1, (ushort4*)Whh1b, G4_ * H_ / 4);
  k_cast4<<<4096, 256, 0, stream>>>((const float4*)Wp,   (ushort4*)Wpb,   V_ * H_ / 4);
  k_bias<<<16, 256, 0, stream>>>(bih0, bhh0, b0s, G4_);
  k_bias<<<16, 256, 0, stream>>>(bih1, bhh1, b1s, G4_);
  k_gather<<<2048, 256, 0, stream>>>(embed, caps, Xbf);
  k_init<<<256, 256, 0, stream>>>(hidden, cell, H0, H1, c0, c1, cbar);
  k_zeropad<<<256, 256, 0, stream>>>(H0 + (size_t)MPAD * H_, H1 + (size_t)MPAD * H_);
  k_zero_t0<<<2000, 256, 0, stream>>>((float4*)out);

  // GEMM1: Xp = X @ W_ih0^T + b0   (M=4096, N=4096, K=512)
  k_gemm1<<<dim3(32, 32), 256, 0, stream>>>(Xbf, Wih0b, b0s, Xp);

  // fused 2-layer recurrence (192 co-resident blocks, R8-verified lockstep)
  k_fused<<<192, 256, 0, stream>>>(Whh0b, Whh1b, Wih1b, Xp, H0, H1, c0, c1, b1s,
                                   cbar, cbar + 64 * FPAD);

  // GEMM3: logits = H1[1..63] @ Wp^T + bp -> out[:,1:,:]
  // (M=4096(4032), N=32000, K=1024; 256^2 tile, counted vmcnt, swizzled LDS)
  k_gemm3<<<2000, 512, 0, stream>>>(H1 + (size_t)B_ * H_, Wpb, bp, out);
}